// Round 2
// baseline (379.885 us; speedup 1.0000x reference)
//
#include <hip/hip_runtime.h>

#define NQ   7
#define DIM  128   // 2^7

// One wave per block; each thread owns one full 128-float row in registers,
// loaded directly with 32x global_load_dwordx4 (512B contiguous per lane).
// No LDS input staging, no barriers in the hot path -> no vmcnt(0) drains.
// Normalization deferred: outputs scaled by 1/ss at the end (gates are
// orthogonal, CZ is diagonal ±1, so probs scale by 1/ss exactly).
__global__ __launch_bounds__(64, 3)
void qnat_kernel(const float* __restrict__ embed,
                 const float* __restrict__ theta,
                 float* __restrict__ out)
{
    const int lane = threadIdx.x;                       // 0..63
    const size_t row = (size_t)blockIdx.x * 64 + lane;
    const float4* __restrict__ g4 =
        reinterpret_cast<const float4*>(embed) + row * 32;

    float st[DIM];
#pragma unroll
    for (int j = 0; j < 32; ++j) {
        const float4 v = g4[j];
        st[4 * j + 0] = v.x;
        st[4 * j + 1] = v.y;
        st[4 * j + 2] = v.z;
        st[4 * j + 3] = v.w;
    }

    // ---- squared norm (normalization deferred to the epilogue) ----
    float ss = 0.f;
#pragma unroll
    for (int i = 0; i < DIM; ++i) ss = fmaf(st[i], st[i], ss);

    // ---- 2 layers of (7 RY gates + CZ ladder phase) ----
#pragma unroll
    for (int d = 0; d < 2; ++d) {
#pragma unroll
        for (int q = 0; q < NQ; ++q) {
            const float half = 0.5f * theta[d * NQ + q];
            const float c_ = __cosf(half);
            const float s_ = __sinf(half);
            const int lo = 1 << q;
#pragma unroll
            for (int p = 0; p < 64; ++p) {
                const int i0 = ((p >> q) << (q + 1)) | (p & (lo - 1));
                const int i1 = i0 | lo;
                const float a0 = st[i0], a1 = st[i1];
                st[i0] = fmaf(c_, a0, -s_ * a1);
                st[i1] = fmaf(s_, a0,  c_ * a1);
            }
        }
        // CZ phase: compile-time ±1 per index; negations fold into FMA
        // input modifiers downstream.
#pragma unroll
        for (int i = 0; i < DIM; ++i) {
            int par = 0;
#pragma unroll
            for (int j = 0; j < NQ - 1; ++j)
                par ^= ((i >> j) & 1) & ((i >> (j + 1)) & 1);
            if (par) st[i] = -st[i];
        }
    }

    // ---- probs (unnormalized) ----
#pragma unroll
    for (int i = 0; i < DIM; ++i) st[i] *= st[i];

    // ---- out[k] = sum_i probs[i]*(1-2*bit_k(i)) : halving sum/diff tree ----
    float o[NQ];
#pragma unroll
    for (int k = 0; k < NQ; ++k) {
        const int n = DIM >> (k + 1);
        float acc = 0.f;
#pragma unroll
        for (int i = 0; i < 64; ++i) {
            if (i < n) {
                const float a = st[2 * i], b = st[2 * i + 1];
                acc += a - b;
                st[i] = a + b;     // safe in-place: write idx i <= read idx 2i
            }
        }
        o[k] = acc;
    }

    // deferred normalization: probs scale by 1/ss
    const float invss = __builtin_amdgcn_rcpf(ss);
#pragma unroll
    for (int k = 0; k < NQ; ++k) o[k] *= invss;

    // ---- repack through LDS for coalesced stores ----
    __shared__ float lds[64 * NQ];
#pragma unroll
    for (int k = 0; k < NQ; ++k) lds[lane * NQ + k] = o[k];
    __syncthreads();
    float* __restrict__ ob = out + (size_t)blockIdx.x * (64 * NQ);
#pragma unroll
    for (int k = 0; k < NQ; ++k) ob[k * 64 + lane] = lds[k * 64 + lane];
}

extern "C" void kernel_launch(void* const* d_in, const int* in_sizes, int n_in,
                              void* d_out, int out_size, void* d_ws, size_t ws_size,
                              hipStream_t stream)
{
    const float* embed = (const float*)d_in[0];
    const float* theta = (const float*)d_in[1];
    float* out = (float*)d_out;
    const int batch = in_sizes[0] / DIM;          // 262144
    dim3 grid(batch / 64), block(64);
    hipLaunchKernelGGL(qnat_kernel, grid, block, 0, stream, embed, theta, out);
}

// Round 3
// 254.165 us; speedup vs baseline: 1.4946x; 1.4946x over previous
//
#include <hip/hip_runtime.h>

#define NQ   7
#define DIM  128   // 2^7

// One wave per block; each thread owns one full 128-float row in registers,
// loaded directly with 32x global_load_dwordx4 (512B contiguous per lane).
// __launch_bounds__(64,2): 256-VGPR cap — st[128]+temps (~150 VGPR) must NOT
// spill (round 2 with the 170-cap spilled: 405 MB scratch writes, 250 us).
__global__ __launch_bounds__(64, 2)
void qnat_kernel(const float* __restrict__ embed,
                 const float* __restrict__ theta,
                 float* __restrict__ out)
{
    const int lane = threadIdx.x;                       // 0..63
    const size_t row = (size_t)blockIdx.x * 64 + lane;
    const float4* __restrict__ g4 =
        reinterpret_cast<const float4*>(embed) + row * 32;

    alignas(16) float st[DIM];
#pragma unroll
    for (int j = 0; j < 32; ++j)
        *reinterpret_cast<float4*>(&st[4 * j]) = g4[j];

    // ---- squared norm (normalization deferred to the epilogue) ----
    float ss = 0.f;
#pragma unroll
    for (int i = 0; i < DIM; ++i) ss = fmaf(st[i], st[i], ss);

    // ---- 2 layers of (7 RY gates + CZ ladder phase) ----
#pragma unroll
    for (int d = 0; d < 2; ++d) {
#pragma unroll
        for (int q = 0; q < NQ; ++q) {
            const float half = 0.5f * theta[d * NQ + q];
            const float c_ = __cosf(half);
            const float s_ = __sinf(half);
            const int lo = 1 << q;
#pragma unroll
            for (int p = 0; p < 64; ++p) {
                const int i0 = ((p >> q) << (q + 1)) | (p & (lo - 1));
                const int i1 = i0 | lo;
                const float a0 = st[i0], a1 = st[i1];
                st[i0] = fmaf(c_, a0, -s_ * a1);
                st[i1] = fmaf(s_, a0,  c_ * a1);
            }
        }
        // CZ phase: compile-time ±1 per index (sign flip = 1 v_xor)
#pragma unroll
        for (int i = 0; i < DIM; ++i) {
            int par = 0;
#pragma unroll
            for (int j = 0; j < NQ - 1; ++j)
                par ^= ((i >> j) & 1) & ((i >> (j + 1)) & 1);
            if (par) st[i] = -st[i];
        }
    }

    // ---- probs (unnormalized) ----
#pragma unroll
    for (int i = 0; i < DIM; ++i) st[i] *= st[i];

    // ---- out[k] = sum_i probs[i]*(1-2*bit_k(i)) : halving sum/diff tree ----
    float o[NQ];
#pragma unroll
    for (int k = 0; k < NQ; ++k) {
        const int n = DIM >> (k + 1);
        float acc = 0.f;
#pragma unroll
        for (int i = 0; i < 64; ++i) {
            if (i < n) {
                const float a = st[2 * i], b = st[2 * i + 1];
                acc += a - b;
                st[i] = a + b;     // safe in-place: write idx i <= read idx 2i
            }
        }
        o[k] = acc;
    }

    // deferred normalization: probs scale by 1/ss
    const float invss = __builtin_amdgcn_rcpf(ss);
#pragma unroll
    for (int k = 0; k < NQ; ++k) o[k] *= invss;

    // ---- repack through LDS for coalesced stores ----
    __shared__ float lds[64 * NQ];
#pragma unroll
    for (int k = 0; k < NQ; ++k) lds[lane * NQ + k] = o[k];
    __syncthreads();
    float* __restrict__ ob = out + (size_t)blockIdx.x * (64 * NQ);
#pragma unroll
    for (int k = 0; k < NQ; ++k) ob[k * 64 + lane] = lds[k * 64 + lane];
}

extern "C" void kernel_launch(void* const* d_in, const int* in_sizes, int n_in,
                              void* d_out, int out_size, void* d_ws, size_t ws_size,
                              hipStream_t stream)
{
    const float* embed = (const float*)d_in[0];
    const float* theta = (const float*)d_in[1];
    float* out = (float*)d_out;
    const int batch = in_sizes[0] / DIM;          // 262144
    dim3 grid(batch / 64), block(64);
    hipLaunchKernelGGL(qnat_kernel, grid, block, 0, stream, embed, theta, out);
}

// Round 4
// 202.868 us; speedup vs baseline: 1.8726x; 1.2529x over previous
//
#include <hip/hip_runtime.h>
#include <utility>

#define NQ   7
#define DIM  128   // 2^7

// Compile-time for: every iteration gets a constexpr index, so there are NO
// runtime loops over the state array in the IR. This lets the FIRST SROA run
// scalarize st[128] into SSA values -> guaranteed register residency.
// (Rounds 2-3 proved the pragma-unroll version leaves st[] in scratch:
//  WRITE_SIZE 170-405 MB = 512 B/thread of scratch stores, VGPR_Count <=128.)
template<class F, int... I>
__device__ __forceinline__ void static_for_impl(F&& f, std::integer_sequence<int, I...>) {
    (f(std::integral_constant<int, I>{}), ...);
}
template<int N, class F>
__device__ __forceinline__ void static_for(F&& f) {
    static_for_impl(static_cast<F&&>(f), std::make_integer_sequence<int, N>{});
}

__global__ __launch_bounds__(64, 2)
void qnat_kernel(const float* __restrict__ embed,
                 const float* __restrict__ theta,
                 float* __restrict__ out)
{
    const int lane = threadIdx.x;                       // 0..63
    const size_t row = (size_t)blockIdx.x * 64 + lane;
    const float4* __restrict__ g4 =
        reinterpret_cast<const float4*>(embed) + row * 32;

    float st[DIM];

    // ---- load own row: 32x dwordx4, constant-indexed scatter into st ----
    static_for<32>([&](auto J) {
        constexpr int j = J.value;
        const float4 v = g4[j];
        st[4 * j + 0] = v.x;
        st[4 * j + 1] = v.y;
        st[4 * j + 2] = v.z;
        st[4 * j + 3] = v.w;
    });

    // ---- squared norm (normalization deferred to the epilogue) ----
    float ss = 0.f;
    static_for<DIM>([&](auto I) {
        constexpr int i = I.value;
        ss = fmaf(st[i], st[i], ss);
    });

    // ---- 2 layers of (7 RY gates + CZ ladder phase) ----
    static_for<2>([&](auto D) {
        constexpr int d = D.value;
        static_for<NQ>([&](auto Q) {
            constexpr int q = Q.value;
            const float half = 0.5f * theta[d * NQ + q];
            const float c_ = __cosf(half);
            const float s_ = __sinf(half);
            static_for<64>([&](auto P) {
                constexpr int p  = P.value;
                constexpr int lo = 1 << q;
                constexpr int i0 = ((p >> q) << (q + 1)) | (p & (lo - 1));
                constexpr int i1 = i0 | lo;
                const float a0 = st[i0], a1 = st[i1];
                st[i0] = fmaf(c_, a0, -s_ * a1);
                st[i1] = fmaf(s_, a0,  c_ * a1);
            });
        });
        // CZ ladder phase: parity of adjacent-bit products = popcount(i & i>>1) & 1
        static_for<DIM>([&](auto I) {
            constexpr int i = I.value;
            constexpr int par = __builtin_popcount(i & (i >> 1)) & 1;
            if constexpr (par) st[i] = -st[i];
        });
    });

    // ---- probs (unnormalized) ----
    static_for<DIM>([&](auto I) {
        constexpr int i = I.value;
        st[i] *= st[i];
    });

    // ---- out[k] = sum_i probs[i]*(1-2*bit_k(i)) : halving sum/diff tree ----
    float o[NQ];
    static_for<NQ>([&](auto K) {
        constexpr int k = K.value;
        constexpr int n = DIM >> (k + 1);
        float acc = 0.f;
        static_for<64>([&](auto I) {
            constexpr int i = I.value;
            if constexpr (i < n) {
                const float a = st[2 * i], b = st[2 * i + 1];
                acc += a - b;
                st[i] = a + b;     // in-place safe: write idx i <= read idx 2i
            }
        });
        o[k] = acc;
    });

    // deferred normalization: probs scale by 1/ss exactly (gates orthogonal,
    // CZ diagonal +-1)
    const float invss = __builtin_amdgcn_rcpf(ss);
    static_for<NQ>([&](auto K) { o[K.value] *= invss; });

    // ---- repack through LDS for coalesced stores ----
    __shared__ float lds[64 * NQ];
    static_for<NQ>([&](auto K) {
        constexpr int k = K.value;
        lds[lane * NQ + k] = o[k];
    });
    __syncthreads();
    float* __restrict__ ob = out + (size_t)blockIdx.x * (64 * NQ);
    static_for<NQ>([&](auto K) {
        constexpr int k = K.value;
        ob[k * 64 + lane] = lds[k * 64 + lane];
    });
}

extern "C" void kernel_launch(void* const* d_in, const int* in_sizes, int n_in,
                              void* d_out, int out_size, void* d_ws, size_t ws_size,
                              hipStream_t stream)
{
    const float* embed = (const float*)d_in[0];
    const float* theta = (const float*)d_in[1];
    float* out = (float*)d_out;
    const int batch = in_sizes[0] / DIM;          // 262144
    dim3 grid(batch / 64), block(64);
    hipLaunchKernelGGL(qnat_kernel, grid, block, 0, stream, embed, theta, out);
}